// Round 1
// baseline (714.108 us; speedup 1.0000x reference)
//
#include <hip/hip_runtime.h>
#include <cmath>

// SimpleHeteroGNN on MI355X — Round 17.
// R16 (691us): fp8 gather copies. This round: two-phase fill.
// Theory: fill_k's 110MB WRITE vs 24.6MB col payload = partial-line eviction
// amplification — the 12MB/XCD edge stream thrashes the 4MB L2 that must hold
// the ~3MB hot col/cnt scatter region. Phase A (bin_k) reads edges ONCE and
// routes them into per-XCD-range buckets with coalesced appends (LDS staging,
// ballot-aggregated counters). Phase B (fill2_k) drains only the local 1.25MB
// bucket stream per XCD -> col lines stay L2-resident until full.

#define NUSR 100000
#define NMOV 20000
#define NEDG 1000000
#define NEUU 500000
#define DH 128

// padded adjacency capacities (degree means 50/10/5, std 7.1/3.2/2.2; guarded)
#define CAPM 96
#define CAPU 32
#define CAPUU 24

#define MRNG (NMOV / 8)   // 2500  (12 bits local)
#define URNG (NUSR / 8)   // 12500 (14 bits local)

// two-phase fill geometry
#define NBINB 977         // bin_k blocks: 977*1024 >= NEDG, 977*512 >= NEUU
#define LCAPR 224         // LDS per-bin cap, rated (mean 128, +9 sigma)
#define LCAPUB 128        // LDS per-bin cap, uu (mean 64, +8.5 sigma)
#define BKCAP 131072      // global bucket cap, rated (mean 125000, +18 sigma)
#define BKCAPU 65536      // global bucket cap, uu (mean 62500, +13 sigma)
#define NF2B 1024         // fill2_k blocks (128 per XCD)

// lin block ranges
#define GLU ((NUSR + 127) / 128)        // 782
#define GLM ((NMOV + 127) / 128)        // 157

typedef unsigned short ushort_t;
typedef unsigned char uchar_t;
typedef __attribute__((ext_vector_type(8))) short short8;
typedef __attribute__((ext_vector_type(4))) float f32x4;
typedef __attribute__((ext_vector_type(2))) float f32x2;

__device__ __forceinline__ ushort_t f2bf(float f) {
  unsigned u = __float_as_uint(f);
  u += 0x7FFFu + ((u >> 16) & 1u);
  return (ushort_t)(u >> 16);
}
__device__ __forceinline__ uchar_t f2fp8(float v) {
  return (uchar_t)(__builtin_amdgcn_cvt_pk_fp8_f32(v, v, 0, false) & 0xFF);
}
__device__ __forceinline__ void fp8x8_to_f32(uint2 v, float* f) {
  f32x2 a = __builtin_amdgcn_cvt_pk_f32_fp8((int)v.x, false);
  f32x2 b = __builtin_amdgcn_cvt_pk_f32_fp8((int)v.x, true);
  f32x2 c = __builtin_amdgcn_cvt_pk_f32_fp8((int)v.y, false);
  f32x2 d = __builtin_amdgcn_cvt_pk_f32_fp8((int)v.y, true);
  f[0] = a.x; f[1] = a.y; f[2] = b.x; f[3] = b.y;
  f[4] = c.x; f[5] = c.y; f[6] = d.x; f[7] = d.y;
}
__device__ __forceinline__ int ntl(const int* p) { return __builtin_nontemporal_load(p); }
__device__ __forceinline__ unsigned ntl(const unsigned* p) { return __builtin_nontemporal_load(p); }
__device__ __forceinline__ ushort_t ntl(const ushort_t* p) { return __builtin_nontemporal_load(p); }

// ---------- fused weight prep + BN params + cnt/bcnt zero ----------
struct PrepArgs {
  const float* Wl[6];
  const float* Wr[6];
};
__global__ __launch_bounds__(256) void prep_all_k(
    PrepArgs pa, ushort_t* __restrict__ Wt,
    const float* __restrict__ W_user, const float* __restrict__ W_movie,
    ushort_t* __restrict__ WtU, ushort_t* __restrict__ WtM,
    const float* __restrict__ p1b, const float* __restrict__ gamma,
    const float* __restrict__ beta, const float* __restrict__ mean,
    const float* __restrict__ var,
    float* __restrict__ SEP, float* __restrict__ TEP,
    int* __restrict__ cntbuf)
{
  int blk = blockIdx.x;
  if (blk < 768) {
    int wi = blk >> 7;
    int idx = (blk & 127) * 256 + threadIdx.x;
    int n = idx >> 8, k = idx & 255;
    const float* Wl = pa.Wl[wi];
    const float* Wr = pa.Wr[wi];
    float v = (k < DH) ? Wl[k * DH + n] : Wr[(k - DH) * DH + n];
    Wt[(size_t)wi * 32768 + n * 256 + k] = f2bf(v);
  } else if (blk < 800) {
    int idx = (blk - 768) * 256 + threadIdx.x;
    int n = idx >> 6, k = idx & 63;
    WtU[n * 64 + k] = f2bf(W_user[k * DH + n]);
  } else if (blk < 864) {
    int idx = (blk - 800) * 256 + threadIdx.x;
    int n = idx >> 7, k = idx & 127;
    WtM[n * 128 + k] = f2bf(W_movie[k * DH + n]);
  } else if (blk == 864) {
    int f = threadIdx.x;
    if (f < DH) {
      float sc = gamma[f] * rsqrtf(var[f] + 1e-5f);
      SEP[f] = sc;
      TEP[f] = (p1b[f] - mean[f]) * sc + beta[f];
    }
  } else {
    int idx = (blk - 865) * 256 + threadIdx.x;  // int4 index
    if (idx < (NMOV + 2 * NUSR + 32) / 4) ((int4*)cntbuf)[idx] = make_int4(0, 0, 0, 0);
  }
}

// ---------- phase A: bin edges into per-XCD-range buckets ----------
__device__ __forceinline__ void bin_scatter(
    bool val, int bin, unsigned entry,
    int* __restrict__ lcnt, unsigned* __restrict__ sbuf, int stride, int lane)
{
#pragma unroll
  for (int b = 0; b < 8; ++b) {
    bool hit = val && (bin == b);
    unsigned long long mk = __ballot(hit);
    if (mk == 0ull) continue;  // wave-uniform
    int first = (int)__ffsll(mk) - 1;
    int base = 0;
    if (lane == first) base = atomicAdd(&lcnt[b], (int)__popcll(mk));
    base = __shfl(base, first);
    if (hit) {
      int pre = (int)__popcll(mk & ((1ull << lane) - 1ull));
      int o = base + pre;
      if (o < stride) sbuf[b * stride + o] = entry;
    }
  }
}

__global__ __launch_bounds__(256) void bin_k(
    const int* __restrict__ rsrc, const int* __restrict__ rdst,
    const int* __restrict__ usrc, const int* __restrict__ udst,
    unsigned* __restrict__ bkt_d, unsigned* __restrict__ bkt_s,
    unsigned* __restrict__ bkt_u, int* __restrict__ bcnt)
{
  __shared__ unsigned sb_d[8][LCAPR];
  __shared__ unsigned sb_s[8][LCAPR];
  __shared__ unsigned sb_u[8][LCAPUB];
  __shared__ int lcnt[24];
  __shared__ int gbase[24];
  const int tid = threadIdx.x;
  const int lane = tid & 63;
  const int wave = tid >> 6;
  if (tid < 24) lcnt[tid] = 0;
  __syncthreads();
  const int c = blockIdx.x;
#pragma unroll
  for (int it = 0; it < 4; ++it) {
    int e = c * 1024 + it * 256 + tid;
    bool v = (e < NEDG);
    int s = 0, d = 0;
    if (v) { s = ntl(&rsrc[e]); d = ntl(&rdst[e]); }
    int bd = d / MRNG;  // 0..7
    unsigned ed = (unsigned)(d - bd * MRNG) | ((unsigned)s << 12);   // 12+17 bits
    bin_scatter(v, bd, ed, &lcnt[0], &sb_d[0][0], LCAPR, lane);
    int bs = s / URNG;
    unsigned es = (unsigned)(s - bs * URNG) | ((unsigned)d << 14);   // 14+15 bits
    bin_scatter(v, bs, es, &lcnt[8], &sb_s[0][0], LCAPR, lane);
    if (it < 2) {
      int e2 = c * 512 + it * 256 + tid;
      bool v2 = (e2 < NEUU);
      int s2 = 0, d2 = 0;
      if (v2) { s2 = ntl(&usrc[e2]); d2 = ntl(&udst[e2]); }
      int bu = d2 / URNG;
      unsigned eu = (unsigned)(d2 - bu * URNG) | ((unsigned)s2 << 14); // 14+17 bits
      bin_scatter(v2, bu, eu, &lcnt[16], &sb_u[0][0], LCAPUB, lane);
    }
  }
  __syncthreads();
  if (tid < 24) {
    int cap = (tid < 16) ? LCAPR : LCAPUB;
    int n = lcnt[tid];
    if (n > cap) n = cap;
    lcnt[tid] = n;
    gbase[tid] = atomicAdd(&bcnt[tid], n);
  }
  __syncthreads();
  for (int t = wave; t < 24; t += 4) {
    int g = t >> 3, b = t & 7;
    const unsigned* sb;
    unsigned* gp;
    int bkcap;
    if (g == 0)      { sb = &sb_d[b][0]; gp = bkt_d + (size_t)b * BKCAP;  bkcap = BKCAP; }
    else if (g == 1) { sb = &sb_s[b][0]; gp = bkt_s + (size_t)b * BKCAP;  bkcap = BKCAP; }
    else             { sb = &sb_u[b][0]; gp = bkt_u + (size_t)b * BKCAPU; bkcap = BKCAPU; }
    int n = lcnt[t];
    int gb = gbase[t];
    if (gb + n > bkcap) n = bkcap - gb;
    for (int i = lane; i < n; i += 64) gp[gb + i] = sb[i];
  }
}

// ---------- phase B: per-XCD drain of local buckets (atomics + col stores) ----------
__global__ __launch_bounds__(256) void fill2_k(
    const unsigned* __restrict__ bkt_d, const unsigned* __restrict__ bkt_s,
    const unsigned* __restrict__ bkt_u, const int* __restrict__ bcnt,
    int* __restrict__ cnt_m, int* __restrict__ cnt_u, int* __restrict__ cnt_uu,
    int* __restrict__ col_m, ushort_t* __restrict__ col_u, int* __restrict__ col_uu)
{
  const int xr = (int)blockIdx.x & 7;
  const int sl = (int)blockIdx.x >> 3;
  const int ns = (int)gridDim.x >> 3;
  const int tid = threadIdx.x;
  // rated, binned by destination movie
  {
    int n = bcnt[xr];
    if (n > BKCAP) n = BKCAP;
    const unsigned* B = bkt_d + (size_t)xr * BKCAP;
    const int dbase = xr * MRNG;
    for (int i = sl * 512 + tid; i < n; i += ns * 512) {
      unsigned v = ntl(&B[i]);
      int j = i + 256;
      unsigned v2 = (j < n) ? ntl(&B[j]) : 0u;
      int d = dbase + (int)(v & 4095u);
      int s = (int)(v >> 12);
      int o = atomicAdd(&cnt_m[d], 1);
      if (o < CAPM) col_m[(size_t)d * CAPM + o] = s;
      if (j < n) {
        int d2 = dbase + (int)(v2 & 4095u);
        int s2 = (int)(v2 >> 12);
        int o2 = atomicAdd(&cnt_m[d2], 1);
        if (o2 < CAPM) col_m[(size_t)d2 * CAPM + o2] = s2;
      }
    }
  }
  // rated, binned by source user
  {
    int n = bcnt[8 + xr];
    if (n > BKCAP) n = BKCAP;
    const unsigned* B = bkt_s + (size_t)xr * BKCAP;
    const int ubase = xr * URNG;
    for (int i = sl * 512 + tid; i < n; i += ns * 512) {
      unsigned v = ntl(&B[i]);
      int j = i + 256;
      unsigned v2 = (j < n) ? ntl(&B[j]) : 0u;
      int s = ubase + (int)(v & 16383u);
      int d = (int)(v >> 14);
      int o = atomicAdd(&cnt_u[s], 1);
      if (o < CAPU) col_u[(size_t)s * CAPU + o] = (ushort_t)d;
      if (j < n) {
        int s2 = ubase + (int)(v2 & 16383u);
        int d2 = (int)(v2 >> 14);
        int o2 = atomicAdd(&cnt_u[s2], 1);
        if (o2 < CAPU) col_u[(size_t)s2 * CAPU + o2] = (ushort_t)d2;
      }
    }
  }
  // uu, binned by destination user
  {
    int n = bcnt[16 + xr];
    if (n > BKCAPU) n = BKCAPU;
    const unsigned* B = bkt_u + (size_t)xr * BKCAPU;
    const int ubase = xr * URNG;
    for (int i = sl * 512 + tid; i < n; i += ns * 512) {
      unsigned v = ntl(&B[i]);
      int j = i + 256;
      unsigned v2 = (j < n) ? ntl(&B[j]) : 0u;
      int d = ubase + (int)(v & 16383u);
      int s = (int)(v >> 14);
      int o = atomicAdd(&cnt_uu[d], 1);
      if (o < CAPUU) col_uu[(size_t)d * CAPUU + o] = s;
      if (j < n) {
        int d2 = ubase + (int)(v2 & 16383u);
        int s2 = (int)(v2 >> 14);
        int o2 = atomicAdd(&cnt_uu[d2], 1);
        if (o2 < CAPUU) col_uu[(size_t)d2 * CAPUU + o2] = s2;
      }
    }
  }
}

// ---------- lin GEMM body (fp32 A converted in-register; bf16 + fp8 out) ----------
template <int K>
__device__ __forceinline__ void lin_body(
    int lblk, const float* __restrict__ X, const ushort_t* __restrict__ Wt,
    const float* __restrict__ b, ushort_t* __restrict__ Y,
    uchar_t* __restrict__ Y8, int N)
{
  const int wave = threadIdx.x >> 6;
  const int lane = threadIdx.x & 63;
  const int row0 = (lblk * 4 + wave) * 32;
  if (row0 >= N) return;
  const int lm = lane & 15;
  const int koff = (lane >> 4) * 8;

  f32x4 acc[2][8];
#pragma unroll
  for (int a = 0; a < 2; ++a)
#pragma unroll
    for (int nt = 0; nt < 8; ++nt) acc[a][nt] = (f32x4){0.f, 0.f, 0.f, 0.f};

#pragma unroll
  for (int ks = 0; ks < K / 32; ++ks) {
    short8 af[2];
#pragma unroll
    for (int a = 0; a < 2; ++a) {
      const float* p = X + (size_t)(row0 + a * 16 + lm) * K + ks * 32 + koff;
      float4 v0 = *(const float4*)p;
      float4 v1 = *(const float4*)(p + 4);
      short8 s;
      s[0] = (short)f2bf(v0.x); s[1] = (short)f2bf(v0.y);
      s[2] = (short)f2bf(v0.z); s[3] = (short)f2bf(v0.w);
      s[4] = (short)f2bf(v1.x); s[5] = (short)f2bf(v1.y);
      s[6] = (short)f2bf(v1.z); s[7] = (short)f2bf(v1.w);
      af[a] = s;
    }
#pragma unroll
    for (int nt = 0; nt < 8; ++nt) {
      short8 bf = *(const short8*)&Wt[(nt * 16 + lm) * K + ks * 32 + koff];
      acc[0][nt] = __builtin_amdgcn_mfma_f32_16x16x32_bf16(af[0], bf, acc[0][nt], 0, 0, 0);
      acc[1][nt] = __builtin_amdgcn_mfma_f32_16x16x32_bf16(af[1], bf, acc[1][nt], 0, 0, 0);
    }
  }

  const int quad = lane >> 4;
#pragma unroll
  for (int nt = 0; nt < 8; ++nt) {
    int f = nt * 16 + lm;
    float bv = b[f];
#pragma unroll
    for (int a = 0; a < 2; ++a) {
#pragma unroll
      for (int reg = 0; reg < 4; ++reg) {
        int r = row0 + a * 16 + quad * 4 + reg;
        float val = fmaxf(acc[a][nt][reg] + bv, 0.f);
        Y[(size_t)r * DH + f] = f2bf(val);
        Y8[(size_t)r * DH + f] = f2fp8(val);
      }
    }
  }
}

// ---------- both input linears in one dispatch ----------
__global__ __launch_bounds__(256) void lin2_k(
    const float* __restrict__ user_feat, const ushort_t* __restrict__ WtU,
    const float* __restrict__ b_user, ushort_t* __restrict__ ux, uchar_t* __restrict__ ux8,
    const float* __restrict__ movie_feat, const ushort_t* __restrict__ WtM,
    const float* __restrict__ b_movie, ushort_t* __restrict__ mx, uchar_t* __restrict__ mx8)
{
  const int blk = blockIdx.x;
  if (blk < GLU) lin_body<64>(blk, user_feat, WtU, b_user, ux, ux8, NUSR);
  else lin_body<128>(blk - GLU, movie_feat, WtM, b_movie, mx, mx8, NMOV);
}

// ---------- gather-mean over padded adjacency, fp8 source: 4 rows/wave ----------
template <typename CT, int CAP, int UNR>
__global__ __launch_bounds__(256) void agg_mean4_k(
    const uchar_t* __restrict__ x8, const int* __restrict__ cnt,
    const CT* __restrict__ col, ushort_t* __restrict__ out, int N)
{
  const int wave = threadIdx.x >> 6;
  const int lane = threadIdx.x & 63;
  const int lm = lane & 15, q = lane >> 4;
  const int row = blockIdx.x * 16 + wave * 4 + q;
  if (row >= N) return;
  const int deg = cnt[row];
  const int e = (deg < CAP) ? deg : CAP;
  const CT* crow = col + (size_t)row * CAP;
  float a[8];
#pragma unroll
  for (int j = 0; j < 8; ++j) a[j] = 0.f;
  int i = 0;
  if (UNR >= 16) {
    for (; i + 15 < e; i += 16) {
      uint2 v[16];
#pragma unroll
      for (int u = 0; u < 16; ++u) {
        int s = (int)ntl(&crow[i + u]);
        v[u] = *(const uint2*)(x8 + (size_t)s * DH + lm * 8);
      }
#pragma unroll
      for (int u = 0; u < 16; ++u) {
        float f0[8];
        fp8x8_to_f32(v[u], f0);
#pragma unroll
        for (int j = 0; j < 8; ++j) a[j] += f0[j];
      }
    }
  }
  if (UNR >= 8) {
    for (; i + 7 < e; i += 8) {
      uint2 v[8];
#pragma unroll
      for (int u = 0; u < 8; ++u) {
        int s = (int)ntl(&crow[i + u]);
        v[u] = *(const uint2*)(x8 + (size_t)s * DH + lm * 8);
      }
#pragma unroll
      for (int u = 0; u < 8; ++u) {
        float f0[8];
        fp8x8_to_f32(v[u], f0);
#pragma unroll
        for (int j = 0; j < 8; ++j) a[j] += f0[j];
      }
    }
  }
  for (; i + 3 < e; i += 4) {
    uint2 v0, v1, v2, v3;
    int s0 = (int)ntl(&crow[i]), s1 = (int)ntl(&crow[i + 1]);
    int s2 = (int)ntl(&crow[i + 2]), s3 = (int)ntl(&crow[i + 3]);
    v0 = *(const uint2*)(x8 + (size_t)s0 * DH + lm * 8);
    v1 = *(const uint2*)(x8 + (size_t)s1 * DH + lm * 8);
    v2 = *(const uint2*)(x8 + (size_t)s2 * DH + lm * 8);
    v3 = *(const uint2*)(x8 + (size_t)s3 * DH + lm * 8);
    float f0[8], f1[8], f2[8], f3[8];
    fp8x8_to_f32(v0, f0); fp8x8_to_f32(v1, f1);
    fp8x8_to_f32(v2, f2); fp8x8_to_f32(v3, f3);
#pragma unroll
    for (int j = 0; j < 8; ++j) a[j] += (f0[j] + f1[j]) + (f2[j] + f3[j]);
  }
  for (; i < e; ++i) {
    uint2 v0 = *(const uint2*)(x8 + (size_t)(int)ntl(&crow[i]) * DH + lm * 8);
    float f0[8];
    fp8x8_to_f32(v0, f0);
#pragma unroll
    for (int j = 0; j < 8; ++j) a[j] += f0[j];
  }
  float inv = 1.f / (float)(deg > 1 ? deg : 1);
  unsigned p0 = f2bf(a[0] * inv) | ((unsigned)f2bf(a[1] * inv) << 16);
  unsigned p1 = f2bf(a[2] * inv) | ((unsigned)f2bf(a[3] * inv) << 16);
  unsigned p2 = f2bf(a[4] * inv) | ((unsigned)f2bf(a[5] * inv) << 16);
  unsigned p3 = f2bf(a[6] * inv) | ((unsigned)f2bf(a[7] * inv) << 16);
  *(int4*)(out + (size_t)row * DH + lm * 8) = make_int4(p0, p1, p2, p3);
}

// ---------- SAGE update GEMM: out = relu([A0|A1] @ WtT + bl), bf16 + opt fp8 ----------
__global__ __launch_bounds__(256) void sage_mfma_k(
    const ushort_t* __restrict__ A0, const ushort_t* __restrict__ A1,
    const ushort_t* __restrict__ Wt, const float* __restrict__ bl,
    ushort_t* __restrict__ out, uchar_t* __restrict__ out8, int N)
{
  const int wave = threadIdx.x >> 6;
  const int lane = threadIdx.x & 63;
  const int row0 = (blockIdx.x * 4 + wave) * 32;
  if (row0 >= N) return;
  const int lm = lane & 15;
  const int koff = (lane >> 4) * 8;

  size_t abase[2];
#pragma unroll
  for (int a = 0; a < 2; ++a) abase[a] = (size_t)(row0 + a * 16 + lm) * DH;

  f32x4 acc[2][8];
#pragma unroll
  for (int a = 0; a < 2; ++a)
#pragma unroll
    for (int nt = 0; nt < 8; ++nt) acc[a][nt] = (f32x4){0.f, 0.f, 0.f, 0.f};

#pragma unroll
  for (int ks = 0; ks < 8; ++ks) {
    short8 af[2];
#pragma unroll
    for (int a = 0; a < 2; ++a) {
      const ushort_t* p = (ks < 4) ? (A0 + abase[a] + ks * 32 + koff)
                                   : (A1 + abase[a] + (ks - 4) * 32 + koff);
      af[a] = *(const short8*)p;
    }
#pragma unroll
    for (int nt = 0; nt < 8; ++nt) {
      short8 bf = *(const short8*)&Wt[(nt * 16 + lm) * 256 + ks * 32 + koff];
      acc[0][nt] = __builtin_amdgcn_mfma_f32_16x16x32_bf16(af[0], bf, acc[0][nt], 0, 0, 0);
      acc[1][nt] = __builtin_amdgcn_mfma_f32_16x16x32_bf16(af[1], bf, acc[1][nt], 0, 0, 0);
    }
  }

  const int quad = lane >> 4;
#pragma unroll
  for (int nt = 0; nt < 8; ++nt) {
    int f = nt * 16 + lm;
    float bv = bl[f];
#pragma unroll
    for (int a = 0; a < 2; ++a) {
#pragma unroll
      for (int reg = 0; reg < 4; ++reg) {
        int r = row0 + a * 16 + quad * 4 + reg;
        float val = fmaxf(acc[a][nt][reg] + bv, 0.f);
        out[(size_t)r * DH + f] = f2bf(val);
        if (out8) out8[(size_t)r * DH + f] = f2fp8(val);
      }
    }
  }
}

// ---------- fused projection GEMMs: pu = ux@Wu, pm = mx@Wm ----------
__device__ __forceinline__ void proj_body(
    int lblk, const ushort_t* __restrict__ A, const ushort_t* __restrict__ Wt,
    int kofs, ushort_t* __restrict__ out, int N)
{
  const int wave = threadIdx.x >> 6;
  const int lane = threadIdx.x & 63;
  const int row0 = (lblk * 4 + wave) * 32;
  if (row0 >= N) return;
  const int lm = lane & 15;
  const int koff = (lane >> 4) * 8;

  size_t abase[2];
#pragma unroll
  for (int a = 0; a < 2; ++a) abase[a] = (size_t)(row0 + a * 16 + lm) * DH;

  f32x4 acc[2][8];
#pragma unroll
  for (int a = 0; a < 2; ++a)
#pragma unroll
    for (int nt = 0; nt < 8; ++nt) acc[a][nt] = (f32x4){0.f, 0.f, 0.f, 0.f};

#pragma unroll
  for (int ks = 0; ks < 4; ++ks) {
    short8 af[2];
#pragma unroll
    for (int a = 0; a < 2; ++a) af[a] = *(const short8*)(A + abase[a] + ks * 32 + koff);
#pragma unroll
    for (int nt = 0; nt < 8; ++nt) {
      short8 bf = *(const short8*)&Wt[(nt * 16 + lm) * 256 + kofs + ks * 32 + koff];
      acc[0][nt] = __builtin_amdgcn_mfma_f32_16x16x32_bf16(af[0], bf, acc[0][nt], 0, 0, 0);
      acc[1][nt] = __builtin_amdgcn_mfma_f32_16x16x32_bf16(af[1], bf, acc[1][nt], 0, 0, 0);
    }
  }

  const int quad = lane >> 4;
#pragma unroll
  for (int nt = 0; nt < 8; ++nt) {
    int f = nt * 16 + lm;
#pragma unroll
    for (int a = 0; a < 2; ++a) {
#pragma unroll
      for (int reg = 0; reg < 4; ++reg) {
        int r = row0 + a * 16 + quad * 4 + reg;
        out[(size_t)r * DH + f] = f2bf(acc[a][nt][reg]);
      }
    }
  }
}

__global__ __launch_bounds__(256) void proj2_k(
    const ushort_t* __restrict__ ux, const ushort_t* __restrict__ mx,
    const ushort_t* __restrict__ Wt, ushort_t* __restrict__ pu,
    ushort_t* __restrict__ pm, int gmU)
{
  if ((int)blockIdx.x < gmU) proj_body(blockIdx.x, ux, Wt, 0, pu, NUSR);
  else proj_body(blockIdx.x - gmU, mx, Wt, DH, pm, NMOV);
}

// ---------- edge-parallel predictor: quarter-wave per edge, EPQ=8 ----------
#define EPQ 8
__global__ __launch_bounds__(256) void ep_edge_k(
    const ushort_t* __restrict__ pu, const ushort_t* __restrict__ pm,
    const int* __restrict__ esrc, const int* __restrict__ edst,
    const float* __restrict__ SEP, const float* __restrict__ TEP,
    const float* __restrict__ p2W, const float* __restrict__ p2b,
    float* __restrict__ out, int nE)
{
  const int lm = threadIdx.x & 15;
  const long tq = ((long)blockIdx.x * 256 + threadIdx.x) >> 4;
  const int f0 = lm * 8;

  float S[8], T8[8], w2[8];
#pragma unroll
  for (int j = 0; j < 8; ++j) {
    S[j] = SEP[f0 + j];
    T8[j] = TEP[f0 + j];
    w2[j] = p2W[f0 + j];
  }
  const float bias2 = p2b[0];

  const long e0 = tq * EPQ;
#pragma unroll
  for (int i = 0; i < EPQ; ++i) {
    long e = e0 + i;
    if (e >= nE) break;
    int s = ntl(&esrc[e]), d = ntl(&edst[e]);
    int4 uv = *(const int4*)(pu + (size_t)s * DH + f0);
    int4 mv = *(const int4*)(pm + (size_t)d * DH + f0);
    float fu[8], fm[8];
    {
      unsigned a0 = (unsigned)uv.x, b0 = (unsigned)uv.y, c0 = (unsigned)uv.z, d0 = (unsigned)uv.w;
      fu[0] = __uint_as_float(a0 << 16); fu[1] = __uint_as_float(a0 & 0xFFFF0000u);
      fu[2] = __uint_as_float(b0 << 16); fu[3] = __uint_as_float(b0 & 0xFFFF0000u);
      fu[4] = __uint_as_float(c0 << 16); fu[5] = __uint_as_float(c0 & 0xFFFF0000u);
      fu[6] = __uint_as_float(d0 << 16); fu[7] = __uint_as_float(d0 & 0xFFFF0000u);
      unsigned a1 = (unsigned)mv.x, b1 = (unsigned)mv.y, c1 = (unsigned)mv.z, d1 = (unsigned)mv.w;
      fm[0] = __uint_as_float(a1 << 16); fm[1] = __uint_as_float(a1 & 0xFFFF0000u);
      fm[2] = __uint_as_float(b1 << 16); fm[3] = __uint_as_float(b1 & 0xFFFF0000u);
      fm[4] = __uint_as_float(c1 << 16); fm[5] = __uint_as_float(c1 & 0xFFFF0000u);
      fm[6] = __uint_as_float(d1 << 16); fm[7] = __uint_as_float(d1 & 0xFFFF0000u);
    }
    float p = 0.f;
#pragma unroll
    for (int j = 0; j < 8; ++j) {
      float h = fmaxf(fmaf(fu[j] + fm[j], S[j], T8[j]), 0.f);
      p = fmaf(h, w2[j], p);
    }
    p += __shfl_xor(p, 1, 16);
    p += __shfl_xor(p, 2, 16);
    p += __shfl_xor(p, 4, 16);
    p += __shfl_xor(p, 8, 16);
    if (lm == 0) out[e] = 4.f / (1.f + expf(-(p + bias2))) + 1.f;
  }
}

extern "C" void kernel_launch(void* const* d_in, const int* in_sizes, int n_in,
                              void* d_out, int out_size, void* d_ws, size_t ws_size,
                              hipStream_t stream)
{
  const float* user_feat = (const float*)d_in[0];
  const float* movie_feat = (const float*)d_in[1];
  const float* W_user = (const float*)d_in[2];
  const float* b_user = (const float*)d_in[3];
  const float* W_movie = (const float*)d_in[4];
  const float* b_movie = (const float*)d_in[5];
  const float* u2m1_Wl = (const float*)d_in[6];
  const float* u2m1_bl = (const float*)d_in[7];
  const float* u2m1_Wr = (const float*)d_in[8];
  const float* m2u1_Wl = (const float*)d_in[9];
  const float* m2u1_bl = (const float*)d_in[10];
  const float* m2u1_Wr = (const float*)d_in[11];
  const float* u2m2_Wl = (const float*)d_in[12];
  const float* u2m2_bl = (const float*)d_in[13];
  const float* u2m2_Wr = (const float*)d_in[14];
  const float* m2u2_Wl = (const float*)d_in[15];
  const float* m2u2_bl = (const float*)d_in[16];
  const float* m2u2_Wr = (const float*)d_in[17];
  const float* u2u_Wl = (const float*)d_in[18];
  const float* u2u_bl = (const float*)d_in[19];
  const float* u2u_Wr = (const float*)d_in[20];
  const float* p1_W = (const float*)d_in[21];
  const float* p1_b = (const float*)d_in[22];
  const float* bn_gamma = (const float*)d_in[23];
  const float* bn_beta = (const float*)d_in[24];
  const float* bn_mean = (const float*)d_in[25];
  const float* bn_var = (const float*)d_in[26];
  const float* p2_W = (const float*)d_in[27];
  const float* p2_b = (const float*)d_in[28];
  const int* rated_src = (const int*)d_in[29];
  const int* rated_dst = (const int*)d_in[30];
  const int* uu_src = (const int*)d_in[31];
  const int* uu_dst = (const int*)d_in[32];

  // ---- workspace layout (~102 MB; R1 used 113 MB so ws fits) ----
  ushort_t* ux = (ushort_t*)d_ws;                       // NU*128 bf16
  ushort_t* mx = ux + (size_t)NUSR * DH;                // NM*128
  ushort_t* agg = mx + (size_t)NMOV * DH;               // NU*128 (reused as pu; buckets alias here pre-lin)
  ushort_t* pm = agg + (size_t)NUSR * DH;               // NM*128
  ushort_t* Wt = pm + (size_t)NMOV * DH;                // 6 * 32768
  ushort_t* WtU = Wt + 6 * 32768;                       // 128*64
  ushort_t* WtM = WtU + 8192;                           // 128*128
  float* SEP = (float*)(WtM + 16384);                   // 128
  float* TEP = SEP + DH;                                // 128
  int* col_m = (int*)(TEP + DH);                        // NMOV*CAPM ints
  ushort_t* col_u = (ushort_t*)(col_m + (size_t)NMOV * CAPM);   // NUSR*CAPU ushorts
  int* col_uu = (int*)(col_u + (size_t)NUSR * CAPU);    // NUSR*CAPUU ints
  int* cntbuf = col_uu + (size_t)NUSR * CAPUU;          // NMOV+2*NUSR+32 (16B-aligned)
  uchar_t* ux8 = (uchar_t*)(cntbuf + (NMOV + 2 * NUSR + 32));   // NU*128 fp8
  uchar_t* mx8 = ux8 + (size_t)NUSR * DH;               // NM*128 fp8
  int* cnt_m = cntbuf;
  int* cnt_u = cntbuf + NMOV;
  int* cnt_uu = cntbuf + NMOV + NUSR;
  int* bcnt = cntbuf + NMOV + 2 * NUSR;                 // 24 bucket cursors

  // edge buckets alias agg (10 MB < 25.6 MB; agg first written by agg_mean4_k,
  // which launches after fill2_k has drained the buckets)
  unsigned* bkt_d = (unsigned*)agg;
  unsigned* bkt_s = bkt_d + (size_t)8 * BKCAP;
  unsigned* bkt_u = bkt_s + (size_t)8 * BKCAP;

  ushort_t* Wt_u2m1 = Wt + 0 * 32768;
  ushort_t* Wt_m2u1 = Wt + 1 * 32768;
  ushort_t* Wt_u2m2 = Wt + 2 * 32768;
  ushort_t* Wt_m2u2 = Wt + 3 * 32768;
  ushort_t* Wt_u2u  = Wt + 4 * 32768;
  ushort_t* Wt_p1   = Wt + 5 * 32768;
  ushort_t* pu = agg;  // alias: agg dead after last sage layer

  // ---- fused weight prep + BN params + cnt/bcnt zero ----
  PrepArgs pa;
  pa.Wl[0] = u2m1_Wl; pa.Wr[0] = u2m1_Wr;
  pa.Wl[1] = m2u1_Wl; pa.Wr[1] = m2u1_Wr;
  pa.Wl[2] = u2m2_Wl; pa.Wr[2] = u2m2_Wr;
  pa.Wl[3] = m2u2_Wl; pa.Wr[3] = m2u2_Wr;
  pa.Wl[4] = u2u_Wl;  pa.Wr[4] = u2u_Wr;
  pa.Wl[5] = p1_W;    pa.Wr[5] = p1_W + DH * DH;
  prep_all_k<<<865 + (NMOV + 2 * NUSR) / 1024 + 1, 256, 0, stream>>>(
      pa, Wt, W_user, W_movie, WtU, WtM,
      p1_b, bn_gamma, bn_beta, bn_mean, bn_var, SEP, TEP, cntbuf);

  // ---- two-phase fill, then input linears (bf16 + fp8 out) ----
  bin_k<<<NBINB, 256, 0, stream>>>(
      rated_src, rated_dst, uu_src, uu_dst, bkt_d, bkt_s, bkt_u, bcnt);
  fill2_k<<<NF2B, 256, 0, stream>>>(
      bkt_d, bkt_s, bkt_u, bcnt, cnt_m, cnt_u, cnt_uu, col_m, col_u, col_uu);
  lin2_k<<<GLU + GLM, 256, 0, stream>>>(
      user_feat, WtU, b_user, ux, ux8, movie_feat, WtM, b_movie, mx, mx8);

  // ---- 5 SAGE layers (fp8 gather + bf16 MFMA) ----
  const int gaM = (NMOV + 15) / 16, gaU = (NUSR + 15) / 16;
  const int gmM = (NMOV + 127) / 128, gmU = (NUSR + 127) / 128;
  // u2m1: gather ux8 -> agg; update mx (+mx8, needed by m2u1 agg)
  agg_mean4_k<int, CAPM, 16><<<gaM, 256, 0, stream>>>(ux8, cnt_m, col_m, agg, NMOV);
  sage_mfma_k<<<gmM, 256, 0, stream>>>(agg, mx, Wt_u2m1, u2m1_bl, mx, mx8, NMOV);
  // m2u1: gather mx8 -> agg; update ux (+ux8, needed by u2m2 agg)
  agg_mean4_k<ushort_t, CAPU, 8><<<gaU, 256, 0, stream>>>(mx8, cnt_u, col_u, agg, NUSR);
  sage_mfma_k<<<gmU, 256, 0, stream>>>(agg, ux, Wt_m2u1, m2u1_bl, ux, ux8, NUSR);
  // u2m2
  agg_mean4_k<int, CAPM, 16><<<gaM, 256, 0, stream>>>(ux8, cnt_m, col_m, agg, NMOV);
  sage_mfma_k<<<gmM, 256, 0, stream>>>(agg, mx, Wt_u2m2, u2m2_bl, mx, mx8, NMOV);
  // m2u2
  agg_mean4_k<ushort_t, CAPU, 8><<<gaU, 256, 0, stream>>>(mx8, cnt_u, col_u, agg, NUSR);
  sage_mfma_k<<<gmU, 256, 0, stream>>>(agg, ux, Wt_m2u2, m2u2_bl, ux, ux8, NUSR);
  // u2u: final user layer; fp8 copy no longer needed afterwards
  agg_mean4_k<int, CAPUU, 8><<<gaU, 256, 0, stream>>>(ux8, cnt_uu, col_uu, agg, NUSR);
  sage_mfma_k<<<gmU, 256, 0, stream>>>(agg, ux, Wt_u2u, u2u_bl, ux, (uchar_t*)nullptr, NUSR);

  // ---- factored edge MLP (bf16 throughout) ----
  proj2_k<<<gmU + gmM, 256, 0, stream>>>(ux, mx, Wt_p1, pu, pm, gmU);
  ep_edge_k<<<(NEDG + 127) / 128, 256, 0, stream>>>(
      pu, pm, rated_src, rated_dst, SEP, TEP, p2_W, p2_b, (float*)d_out, NEDG);
}

// Round 2
// 663.839 us; speedup vs baseline: 1.0757x; 1.0757x over previous
//
#include <hip/hip_runtime.h>
#include <cmath>

// SimpleHeteroGNN on MI355X — Round 18.
// R17 post-mortem: two-phase fill fixed FETCH (47->6MB) but WRITE stayed 95MB
// -> scatter amplification is intrinsic (125K rows open concurrently; 64B
// sectors evict ~4x before full). R18: fine-grained binning (452 node-range
// buckets) so each CSR slice is assembled ENTIRELY in LDS and flushed as
// coalesced full-line int4 streams. Zero global atomics in phase B; phase A
// uses 1 LDS atomic/edge (replaces the O(bins) ballot loop). cnt arrays are
// fully overwritten -> cnt memset deleted from prep.

#define NUSR 100000
#define NMOV 20000
#define NEDG 1000000
#define NEUU 500000
#define DH 128

// padded adjacency capacities (degree means 50/10/5, std 7.1/3.2/2.2; >=6.5
// sigma so they never bind)
#define CAPM 96
#define CAPU 32
#define CAPUU 24

// fine binning geometry: bin range x row cap fits LDS (<=60.3KB)
#define NBD 128
#define WD 157            // 128*157 >= 20000; 157*96*4B = 60288B LDS
#define NBS 128
#define WS 782            // 128*782 >= 100000; 782*32*2B = 50048B LDS
#define NBU 196
#define WU 512            // 196*512 >= 100000; 512*24*4B = 49152B LDS
#define NBT (NBD + NBS + NBU)  // 452

// phase-A per-block LDS staging caps (lambda = 8 / 8 / 2.6; +~10 sigma)
#define LCD 36
#define LCS 36
#define LCU 20
// global bucket caps (mean 7812/7812/2551; +7 sigma)
#define BKD 8448
#define BKS 8448
#define BKU 2944

#define NBINB 977         // 977*1024 >= NEDG, 977*512 >= NEUU

// lin block ranges
#define GLU ((NUSR + 127) / 128)        // 782
#define GLM ((NMOV + 127) / 128)        // 157

typedef unsigned short ushort_t;
typedef unsigned char uchar_t;
typedef __attribute__((ext_vector_type(8))) short short8;
typedef __attribute__((ext_vector_type(4))) float f32x4;
typedef __attribute__((ext_vector_type(2))) float f32x2;

__device__ __forceinline__ ushort_t f2bf(float f) {
  unsigned u = __float_as_uint(f);
  u += 0x7FFFu + ((u >> 16) & 1u);
  return (ushort_t)(u >> 16);
}
__device__ __forceinline__ uchar_t f2fp8(float v) {
  return (uchar_t)(__builtin_amdgcn_cvt_pk_fp8_f32(v, v, 0, false) & 0xFF);
}
__device__ __forceinline__ void fp8x8_to_f32(uint2 v, float* f) {
  f32x2 a = __builtin_amdgcn_cvt_pk_f32_fp8((int)v.x, false);
  f32x2 b = __builtin_amdgcn_cvt_pk_f32_fp8((int)v.x, true);
  f32x2 c = __builtin_amdgcn_cvt_pk_f32_fp8((int)v.y, false);
  f32x2 d = __builtin_amdgcn_cvt_pk_f32_fp8((int)v.y, true);
  f[0] = a.x; f[1] = a.y; f[2] = b.x; f[3] = b.y;
  f[4] = c.x; f[5] = c.y; f[6] = d.x; f[7] = d.y;
}
__device__ __forceinline__ int ntl(const int* p) { return __builtin_nontemporal_load(p); }
__device__ __forceinline__ unsigned ntl(const unsigned* p) { return __builtin_nontemporal_load(p); }
__device__ __forceinline__ ushort_t ntl(const ushort_t* p) { return __builtin_nontemporal_load(p); }

// ---------- fused weight prep + BN params + bcnt zero ----------
struct PrepArgs {
  const float* Wl[6];
  const float* Wr[6];
};
__global__ __launch_bounds__(256) void prep_all_k(
    PrepArgs pa, ushort_t* __restrict__ Wt,
    const float* __restrict__ W_user, const float* __restrict__ W_movie,
    ushort_t* __restrict__ WtU, ushort_t* __restrict__ WtM,
    const float* __restrict__ p1b, const float* __restrict__ gamma,
    const float* __restrict__ beta, const float* __restrict__ mean,
    const float* __restrict__ var,
    float* __restrict__ SEP, float* __restrict__ TEP,
    int* __restrict__ bcnt)
{
  int blk = blockIdx.x;
  if (blk < 768) {
    int wi = blk >> 7;
    int idx = (blk & 127) * 256 + threadIdx.x;
    int n = idx >> 8, k = idx & 255;
    const float* Wl = pa.Wl[wi];
    const float* Wr = pa.Wr[wi];
    float v = (k < DH) ? Wl[k * DH + n] : Wr[(k - DH) * DH + n];
    Wt[(size_t)wi * 32768 + n * 256 + k] = f2bf(v);
  } else if (blk < 800) {
    int idx = (blk - 768) * 256 + threadIdx.x;
    int n = idx >> 6, k = idx & 63;
    WtU[n * 64 + k] = f2bf(W_user[k * DH + n]);
  } else if (blk < 864) {
    int idx = (blk - 800) * 256 + threadIdx.x;
    int n = idx >> 7, k = idx & 127;
    WtM[n * 128 + k] = f2bf(W_movie[k * DH + n]);
  } else {
    int f = threadIdx.x;
    if (f < DH) {
      float sc = gamma[f] * rsqrtf(var[f] + 1e-5f);
      SEP[f] = sc;
      TEP[f] = (p1b[f] - mean[f]) * sc + beta[f];
    }
    for (int i = threadIdx.x; i < NBT; i += 256) bcnt[i] = 0;
  }
}

// ---------- phase A: bin edges into 452 node-range buckets (LDS atomics) ----------
__global__ __launch_bounds__(256) void bin_k(
    const int* __restrict__ rsrc, const int* __restrict__ rdst,
    const int* __restrict__ usrc, const int* __restrict__ udst,
    unsigned* __restrict__ bkt_d, unsigned* __restrict__ bkt_s,
    unsigned* __restrict__ bkt_u, int* __restrict__ bcnt)
{
  __shared__ unsigned sb_d[NBD * LCD];
  __shared__ unsigned sb_s[NBS * LCS];
  __shared__ unsigned sb_u[NBU * LCU];
  __shared__ int lcnt[NBT];
  __shared__ int gbase[NBT];
  const int tid = threadIdx.x;
  for (int i = tid; i < NBT; i += 256) lcnt[i] = 0;
  __syncthreads();
  const int c = blockIdx.x;
#pragma unroll
  for (int it = 0; it < 4; ++it) {
    int e = c * 1024 + it * 256 + tid;
    if (e < NEDG) {
      int s = ntl(&rsrc[e]), d = ntl(&rdst[e]);
      int bd = d / WD;
      int o = atomicAdd(&lcnt[bd], 1);
      if (o < LCD) sb_d[bd * LCD + o] = (unsigned)(d - bd * WD) | ((unsigned)s << 8);
      int bs = s / WS;
      int o2 = atomicAdd(&lcnt[NBD + bs], 1);
      if (o2 < LCS) sb_s[bs * LCS + o2] = (unsigned)(s - bs * WS) | ((unsigned)d << 10);
    }
    if (it < 2) {
      int e2 = c * 512 + it * 256 + tid;
      if (e2 < NEUU) {
        int s2 = ntl(&usrc[e2]), d2 = ntl(&udst[e2]);
        int bu = d2 >> 9;
        int o3 = atomicAdd(&lcnt[NBD + NBS + bu], 1);
        if (o3 < LCU) sb_u[bu * LCU + o3] = (unsigned)(d2 & 511) | ((unsigned)s2 << 9);
      }
    }
  }
  __syncthreads();
  for (int i = tid; i < NBT; i += 256) {
    int cap = (i < NBD + NBS) ? LCD : LCU;
    int n = lcnt[i];
    if (n > cap) n = cap;
    lcnt[i] = n;
    gbase[i] = atomicAdd(&bcnt[i], n);
  }
  __syncthreads();
  const int qw = tid >> 4, lq = tid & 15;
  for (int t = qw; t < NBT; t += 16) {
    int n = lcnt[t];
    int gb = gbase[t];
    unsigned* gp; const unsigned* sp; int cap;
    if (t < NBD)            { gp = bkt_d + (size_t)t * BKD;               sp = sb_d + t * LCD;               cap = BKD; }
    else if (t < NBD + NBS) { gp = bkt_s + (size_t)(t - NBD) * BKS;       sp = sb_s + (t - NBD) * LCS;       cap = BKS; }
    else                    { gp = bkt_u + (size_t)(t - NBD - NBS) * BKU; sp = sb_u + (t - NBD - NBS) * LCU; cap = BKU; }
    if (gb + n > cap) n = cap - gb;
    for (int i = lq; i < n; i += 16) gp[gb + i] = sp[i];
  }
}

// ---------- phase B: build CSR slice fully in LDS, flush coalesced ----------
__global__ __launch_bounds__(256) void csr_k(
    const unsigned* __restrict__ bkt_d, const unsigned* __restrict__ bkt_s,
    const unsigned* __restrict__ bkt_u, const int* __restrict__ bcnt,
    int* __restrict__ cnt_m, int* __restrict__ cnt_u, int* __restrict__ cnt_uu,
    int* __restrict__ col_m, ushort_t* __restrict__ col_u, int* __restrict__ col_uu)
{
  __shared__ int lc[WS];                               // 782 ints (max rows/bin)
  __shared__ alignas(16) unsigned cbuf[WD * CAPM];     // 60288B (max slice)
  const int tid = threadIdx.x;
  const int bid = blockIdx.x;
  if (bid < NBD) {
    const int b = bid;
    const int nr = (NMOV - b * WD < WD) ? (NMOV - b * WD) : WD;
    for (int m = tid; m < nr; m += 256) lc[m] = 0;
    __syncthreads();
    int n = bcnt[b]; if (n > BKD) n = BKD;
    const unsigned* B = bkt_d + (size_t)b * BKD;
    for (int i = tid; i < n; i += 256) {
      unsigned v = ntl(&B[i]);
      int m = (int)(v & 255u);
      int o = atomicAdd(&lc[m], 1);
      if (o < CAPM) cbuf[m * CAPM + o] = v >> 8;
    }
    __syncthreads();
    for (int m = tid; m < nr; m += 256) cnt_m[b * WD + m] = lc[m];
    int4* dst = (int4*)(col_m + (size_t)b * WD * CAPM);
    const int4* src = (const int4*)cbuf;
    const int tot = nr * (CAPM / 4);
    for (int i = tid; i < tot; i += 256) dst[i] = src[i];
  } else if (bid < NBD + NBS) {
    const int b = bid - NBD;
    const int nr = (NUSR - b * WS < WS) ? (NUSR - b * WS) : WS;
    for (int u = tid; u < nr; u += 256) lc[u] = 0;
    __syncthreads();
    int n = bcnt[NBD + b]; if (n > BKS) n = BKS;
    const unsigned* B = bkt_s + (size_t)b * BKS;
    ushort_t* cb16 = (ushort_t*)cbuf;
    for (int i = tid; i < n; i += 256) {
      unsigned v = ntl(&B[i]);
      int u = (int)(v & 1023u);
      int o = atomicAdd(&lc[u], 1);
      if (o < CAPU) cb16[u * CAPU + o] = (ushort_t)(v >> 10);
    }
    __syncthreads();
    for (int u = tid; u < nr; u += 256) cnt_u[b * WS + u] = lc[u];
    int4* dst = (int4*)(col_u + (size_t)b * WS * CAPU);
    const int4* src = (const int4*)cbuf;
    const int tot = nr * (CAPU / 8);                   // nr*64B / 16
    for (int i = tid; i < tot; i += 256) dst[i] = src[i];
  } else {
    const int b = bid - NBD - NBS;
    const int nr = (NUSR - b * WU < WU) ? (NUSR - b * WU) : WU;
    for (int u = tid; u < nr; u += 256) lc[u] = 0;
    __syncthreads();
    int n = bcnt[NBD + NBS + b]; if (n > BKU) n = BKU;
    const unsigned* B = bkt_u + (size_t)b * BKU;
    for (int i = tid; i < n; i += 256) {
      unsigned v = ntl(&B[i]);
      int u = (int)(v & 511u);
      int o = atomicAdd(&lc[u], 1);
      if (o < CAPUU) cbuf[u * CAPUU + o] = v >> 9;
    }
    __syncthreads();
    for (int u = tid; u < nr; u += 256) cnt_uu[b * WU + u] = lc[u];
    int4* dst = (int4*)(col_uu + (size_t)b * WU * CAPUU);
    const int4* src = (const int4*)cbuf;
    const int tot = nr * (CAPUU / 4);
    for (int i = tid; i < tot; i += 256) dst[i] = src[i];
  }
}

// ---------- lin GEMM body (fp32 A converted in-register; bf16 + fp8 out) ----------
template <int K>
__device__ __forceinline__ void lin_body(
    int lblk, const float* __restrict__ X, const ushort_t* __restrict__ Wt,
    const float* __restrict__ b, ushort_t* __restrict__ Y,
    uchar_t* __restrict__ Y8, int N)
{
  const int wave = threadIdx.x >> 6;
  const int lane = threadIdx.x & 63;
  const int row0 = (lblk * 4 + wave) * 32;
  if (row0 >= N) return;
  const int lm = lane & 15;
  const int koff = (lane >> 4) * 8;

  f32x4 acc[2][8];
#pragma unroll
  for (int a = 0; a < 2; ++a)
#pragma unroll
    for (int nt = 0; nt < 8; ++nt) acc[a][nt] = (f32x4){0.f, 0.f, 0.f, 0.f};

#pragma unroll
  for (int ks = 0; ks < K / 32; ++ks) {
    short8 af[2];
#pragma unroll
    for (int a = 0; a < 2; ++a) {
      const float* p = X + (size_t)(row0 + a * 16 + lm) * K + ks * 32 + koff;
      float4 v0 = *(const float4*)p;
      float4 v1 = *(const float4*)(p + 4);
      short8 s;
      s[0] = (short)f2bf(v0.x); s[1] = (short)f2bf(v0.y);
      s[2] = (short)f2bf(v0.z); s[3] = (short)f2bf(v0.w);
      s[4] = (short)f2bf(v1.x); s[5] = (short)f2bf(v1.y);
      s[6] = (short)f2bf(v1.z); s[7] = (short)f2bf(v1.w);
      af[a] = s;
    }
#pragma unroll
    for (int nt = 0; nt < 8; ++nt) {
      short8 bf = *(const short8*)&Wt[(nt * 16 + lm) * K + ks * 32 + koff];
      acc[0][nt] = __builtin_amdgcn_mfma_f32_16x16x32_bf16(af[0], bf, acc[0][nt], 0, 0, 0);
      acc[1][nt] = __builtin_amdgcn_mfma_f32_16x16x32_bf16(af[1], bf, acc[1][nt], 0, 0, 0);
    }
  }

  const int quad = lane >> 4;
#pragma unroll
  for (int nt = 0; nt < 8; ++nt) {
    int f = nt * 16 + lm;
    float bv = b[f];
#pragma unroll
    for (int a = 0; a < 2; ++a) {
#pragma unroll
      for (int reg = 0; reg < 4; ++reg) {
        int r = row0 + a * 16 + quad * 4 + reg;
        float val = fmaxf(acc[a][nt][reg] + bv, 0.f);
        Y[(size_t)r * DH + f] = f2bf(val);
        Y8[(size_t)r * DH + f] = f2fp8(val);
      }
    }
  }
}

// ---------- both input linears in one dispatch ----------
__global__ __launch_bounds__(256) void lin2_k(
    const float* __restrict__ user_feat, const ushort_t* __restrict__ WtU,
    const float* __restrict__ b_user, ushort_t* __restrict__ ux, uchar_t* __restrict__ ux8,
    const float* __restrict__ movie_feat, const ushort_t* __restrict__ WtM,
    const float* __restrict__ b_movie, ushort_t* __restrict__ mx, uchar_t* __restrict__ mx8)
{
  const int blk = blockIdx.x;
  if (blk < GLU) lin_body<64>(blk, user_feat, WtU, b_user, ux, ux8, NUSR);
  else lin_body<128>(blk - GLU, movie_feat, WtM, b_movie, mx, mx8, NMOV);
}

// ---------- gather-mean over padded adjacency, fp8 source: 4 rows/wave ----------
template <typename CT, int CAP, int UNR>
__global__ __launch_bounds__(256) void agg_mean4_k(
    const uchar_t* __restrict__ x8, const int* __restrict__ cnt,
    const CT* __restrict__ col, ushort_t* __restrict__ out, int N)
{
  const int wave = threadIdx.x >> 6;
  const int lane = threadIdx.x & 63;
  const int lm = lane & 15, q = lane >> 4;
  const int row = blockIdx.x * 16 + wave * 4 + q;
  if (row >= N) return;
  const int deg = cnt[row];
  const int e = (deg < CAP) ? deg : CAP;
  const CT* crow = col + (size_t)row * CAP;
  float a[8];
#pragma unroll
  for (int j = 0; j < 8; ++j) a[j] = 0.f;
  int i = 0;
  if (UNR >= 16) {
    for (; i + 15 < e; i += 16) {
      uint2 v[16];
#pragma unroll
      for (int u = 0; u < 16; ++u) {
        int s = (int)ntl(&crow[i + u]);
        v[u] = *(const uint2*)(x8 + (size_t)s * DH + lm * 8);
      }
#pragma unroll
      for (int u = 0; u < 16; ++u) {
        float f0[8];
        fp8x8_to_f32(v[u], f0);
#pragma unroll
        for (int j = 0; j < 8; ++j) a[j] += f0[j];
      }
    }
  }
  if (UNR >= 8) {
    for (; i + 7 < e; i += 8) {
      uint2 v[8];
#pragma unroll
      for (int u = 0; u < 8; ++u) {
        int s = (int)ntl(&crow[i + u]);
        v[u] = *(const uint2*)(x8 + (size_t)s * DH + lm * 8);
      }
#pragma unroll
      for (int u = 0; u < 8; ++u) {
        float f0[8];
        fp8x8_to_f32(v[u], f0);
#pragma unroll
        for (int j = 0; j < 8; ++j) a[j] += f0[j];
      }
    }
  }
  for (; i + 3 < e; i += 4) {
    uint2 v0, v1, v2, v3;
    int s0 = (int)ntl(&crow[i]), s1 = (int)ntl(&crow[i + 1]);
    int s2 = (int)ntl(&crow[i + 2]), s3 = (int)ntl(&crow[i + 3]);
    v0 = *(const uint2*)(x8 + (size_t)s0 * DH + lm * 8);
    v1 = *(const uint2*)(x8 + (size_t)s1 * DH + lm * 8);
    v2 = *(const uint2*)(x8 + (size_t)s2 * DH + lm * 8);
    v3 = *(const uint2*)(x8 + (size_t)s3 * DH + lm * 8);
    float f0[8], f1[8], f2[8], f3[8];
    fp8x8_to_f32(v0, f0); fp8x8_to_f32(v1, f1);
    fp8x8_to_f32(v2, f2); fp8x8_to_f32(v3, f3);
#pragma unroll
    for (int j = 0; j < 8; ++j) a[j] += (f0[j] + f1[j]) + (f2[j] + f3[j]);
  }
  for (; i < e; ++i) {
    uint2 v0 = *(const uint2*)(x8 + (size_t)(int)ntl(&crow[i]) * DH + lm * 8);
    float f0[8];
    fp8x8_to_f32(v0, f0);
#pragma unroll
    for (int j = 0; j < 8; ++j) a[j] += f0[j];
  }
  float inv = 1.f / (float)(deg > 1 ? deg : 1);
  unsigned p0 = f2bf(a[0] * inv) | ((unsigned)f2bf(a[1] * inv) << 16);
  unsigned p1 = f2bf(a[2] * inv) | ((unsigned)f2bf(a[3] * inv) << 16);
  unsigned p2 = f2bf(a[4] * inv) | ((unsigned)f2bf(a[5] * inv) << 16);
  unsigned p3 = f2bf(a[6] * inv) | ((unsigned)f2bf(a[7] * inv) << 16);
  *(int4*)(out + (size_t)row * DH + lm * 8) = make_int4(p0, p1, p2, p3);
}

// ---------- SAGE update GEMM: out = relu([A0|A1] @ WtT + bl), bf16 + opt fp8 ----------
__global__ __launch_bounds__(256) void sage_mfma_k(
    const ushort_t* __restrict__ A0, const ushort_t* __restrict__ A1,
    const ushort_t* __restrict__ Wt, const float* __restrict__ bl,
    ushort_t* __restrict__ out, uchar_t* __restrict__ out8, int N)
{
  const int wave = threadIdx.x >> 6;
  const int lane = threadIdx.x & 63;
  const int row0 = (blockIdx.x * 4 + wave) * 32;
  if (row0 >= N) return;
  const int lm = lane & 15;
  const int koff = (lane >> 4) * 8;

  size_t abase[2];
#pragma unroll
  for (int a = 0; a < 2; ++a) abase[a] = (size_t)(row0 + a * 16 + lm) * DH;

  f32x4 acc[2][8];
#pragma unroll
  for (int a = 0; a < 2; ++a)
#pragma unroll
    for (int nt = 0; nt < 8; ++nt) acc[a][nt] = (f32x4){0.f, 0.f, 0.f, 0.f};

#pragma unroll
  for (int ks = 0; ks < 8; ++ks) {
    short8 af[2];
#pragma unroll
    for (int a = 0; a < 2; ++a) {
      const ushort_t* p = (ks < 4) ? (A0 + abase[a] + ks * 32 + koff)
                                   : (A1 + abase[a] + (ks - 4) * 32 + koff);
      af[a] = *(const short8*)p;
    }
#pragma unroll
    for (int nt = 0; nt < 8; ++nt) {
      short8 bf = *(const short8*)&Wt[(nt * 16 + lm) * 256 + ks * 32 + koff];
      acc[0][nt] = __builtin_amdgcn_mfma_f32_16x16x32_bf16(af[0], bf, acc[0][nt], 0, 0, 0);
      acc[1][nt] = __builtin_amdgcn_mfma_f32_16x16x32_bf16(af[1], bf, acc[1][nt], 0, 0, 0);
    }
  }

  const int quad = lane >> 4;
#pragma unroll
  for (int nt = 0; nt < 8; ++nt) {
    int f = nt * 16 + lm;
    float bv = bl[f];
#pragma unroll
    for (int a = 0; a < 2; ++a) {
#pragma unroll
      for (int reg = 0; reg < 4; ++reg) {
        int r = row0 + a * 16 + quad * 4 + reg;
        float val = fmaxf(acc[a][nt][reg] + bv, 0.f);
        out[(size_t)r * DH + f] = f2bf(val);
        if (out8) out8[(size_t)r * DH + f] = f2fp8(val);
      }
    }
  }
}

// ---------- fused projection GEMMs: pu = ux@Wu, pm = mx@Wm ----------
__device__ __forceinline__ void proj_body(
    int lblk, const ushort_t* __restrict__ A, const ushort_t* __restrict__ Wt,
    int kofs, ushort_t* __restrict__ out, int N)
{
  const int wave = threadIdx.x >> 6;
  const int lane = threadIdx.x & 63;
  const int row0 = (lblk * 4 + wave) * 32;
  if (row0 >= N) return;
  const int lm = lane & 15;
  const int koff = (lane >> 4) * 8;

  size_t abase[2];
#pragma unroll
  for (int a = 0; a < 2; ++a) abase[a] = (size_t)(row0 + a * 16 + lm) * DH;

  f32x4 acc[2][8];
#pragma unroll
  for (int a = 0; a < 2; ++a)
#pragma unroll
    for (int nt = 0; nt < 8; ++nt) acc[a][nt] = (f32x4){0.f, 0.f, 0.f, 0.f};

#pragma unroll
  for (int ks = 0; ks < 4; ++ks) {
    short8 af[2];
#pragma unroll
    for (int a = 0; a < 2; ++a) af[a] = *(const short8*)(A + abase[a] + ks * 32 + koff);
#pragma unroll
    for (int nt = 0; nt < 8; ++nt) {
      short8 bf = *(const short8*)&Wt[(nt * 16 + lm) * 256 + kofs + ks * 32 + koff];
      acc[0][nt] = __builtin_amdgcn_mfma_f32_16x16x32_bf16(af[0], bf, acc[0][nt], 0, 0, 0);
      acc[1][nt] = __builtin_amdgcn_mfma_f32_16x16x32_bf16(af[1], bf, acc[1][nt], 0, 0, 0);
    }
  }

  const int quad = lane >> 4;
#pragma unroll
  for (int nt = 0; nt < 8; ++nt) {
    int f = nt * 16 + lm;
#pragma unroll
    for (int a = 0; a < 2; ++a) {
#pragma unroll
      for (int reg = 0; reg < 4; ++reg) {
        int r = row0 + a * 16 + quad * 4 + reg;
        out[(size_t)r * DH + f] = f2bf(acc[a][nt][reg]);
      }
    }
  }
}

__global__ __launch_bounds__(256) void proj2_k(
    const ushort_t* __restrict__ ux, const ushort_t* __restrict__ mx,
    const ushort_t* __restrict__ Wt, ushort_t* __restrict__ pu,
    ushort_t* __restrict__ pm, int gmU)
{
  if ((int)blockIdx.x < gmU) proj_body(blockIdx.x, ux, Wt, 0, pu, NUSR);
  else proj_body(blockIdx.x - gmU, mx, Wt, DH, pm, NMOV);
}

// ---------- edge-parallel predictor: quarter-wave per edge, EPQ=8 ----------
#define EPQ 8
__global__ __launch_bounds__(256) void ep_edge_k(
    const ushort_t* __restrict__ pu, const ushort_t* __restrict__ pm,
    const int* __restrict__ esrc, const int* __restrict__ edst,
    const float* __restrict__ SEP, const float* __restrict__ TEP,
    const float* __restrict__ p2W, const float* __restrict__ p2b,
    float* __restrict__ out, int nE)
{
  const int lm = threadIdx.x & 15;
  const long tq = ((long)blockIdx.x * 256 + threadIdx.x) >> 4;
  const int f0 = lm * 8;

  float S[8], T8[8], w2[8];
#pragma unroll
  for (int j = 0; j < 8; ++j) {
    S[j] = SEP[f0 + j];
    T8[j] = TEP[f0 + j];
    w2[j] = p2W[f0 + j];
  }
  const float bias2 = p2b[0];

  const long e0 = tq * EPQ;
#pragma unroll
  for (int i = 0; i < EPQ; ++i) {
    long e = e0 + i;
    if (e >= nE) break;
    int s = ntl(&esrc[e]), d = ntl(&edst[e]);
    int4 uv = *(const int4*)(pu + (size_t)s * DH + f0);
    int4 mv = *(const int4*)(pm + (size_t)d * DH + f0);
    float fu[8], fm[8];
    {
      unsigned a0 = (unsigned)uv.x, b0 = (unsigned)uv.y, c0 = (unsigned)uv.z, d0 = (unsigned)uv.w;
      fu[0] = __uint_as_float(a0 << 16); fu[1] = __uint_as_float(a0 & 0xFFFF0000u);
      fu[2] = __uint_as_float(b0 << 16); fu[3] = __uint_as_float(b0 & 0xFFFF0000u);
      fu[4] = __uint_as_float(c0 << 16); fu[5] = __uint_as_float(c0 & 0xFFFF0000u);
      fu[6] = __uint_as_float(d0 << 16); fu[7] = __uint_as_float(d0 & 0xFFFF0000u);
      unsigned a1 = (unsigned)mv.x, b1 = (unsigned)mv.y, c1 = (unsigned)mv.z, d1 = (unsigned)mv.w;
      fm[0] = __uint_as_float(a1 << 16); fm[1] = __uint_as_float(a1 & 0xFFFF0000u);
      fm[2] = __uint_as_float(b1 << 16); fm[3] = __uint_as_float(b1 & 0xFFFF0000u);
      fm[4] = __uint_as_float(c1 << 16); fm[5] = __uint_as_float(c1 & 0xFFFF0000u);
      fm[6] = __uint_as_float(d1 << 16); fm[7] = __uint_as_float(d1 & 0xFFFF0000u);
    }
    float p = 0.f;
#pragma unroll
    for (int j = 0; j < 8; ++j) {
      float h = fmaxf(fmaf(fu[j] + fm[j], S[j], T8[j]), 0.f);
      p = fmaf(h, w2[j], p);
    }
    p += __shfl_xor(p, 1, 16);
    p += __shfl_xor(p, 2, 16);
    p += __shfl_xor(p, 4, 16);
    p += __shfl_xor(p, 8, 16);
    if (lm == 0) out[e] = 4.f / (1.f + expf(-(p + bias2))) + 1.f;
  }
}

extern "C" void kernel_launch(void* const* d_in, const int* in_sizes, int n_in,
                              void* d_out, int out_size, void* d_ws, size_t ws_size,
                              hipStream_t stream)
{
  const float* user_feat = (const float*)d_in[0];
  const float* movie_feat = (const float*)d_in[1];
  const float* W_user = (const float*)d_in[2];
  const float* b_user = (const float*)d_in[3];
  const float* W_movie = (const float*)d_in[4];
  const float* b_movie = (const float*)d_in[5];
  const float* u2m1_Wl = (const float*)d_in[6];
  const float* u2m1_bl = (const float*)d_in[7];
  const float* u2m1_Wr = (const float*)d_in[8];
  const float* m2u1_Wl = (const float*)d_in[9];
  const float* m2u1_bl = (const float*)d_in[10];
  const float* m2u1_Wr = (const float*)d_in[11];
  const float* u2m2_Wl = (const float*)d_in[12];
  const float* u2m2_bl = (const float*)d_in[13];
  const float* u2m2_Wr = (const float*)d_in[14];
  const float* m2u2_Wl = (const float*)d_in[15];
  const float* m2u2_bl = (const float*)d_in[16];
  const float* m2u2_Wr = (const float*)d_in[17];
  const float* u2u_Wl = (const float*)d_in[18];
  const float* u2u_bl = (const float*)d_in[19];
  const float* u2u_Wr = (const float*)d_in[20];
  const float* p1_W = (const float*)d_in[21];
  const float* p1_b = (const float*)d_in[22];
  const float* bn_gamma = (const float*)d_in[23];
  const float* bn_beta = (const float*)d_in[24];
  const float* bn_mean = (const float*)d_in[25];
  const float* bn_var = (const float*)d_in[26];
  const float* p2_W = (const float*)d_in[27];
  const float* p2_b = (const float*)d_in[28];
  const int* rated_src = (const int*)d_in[29];
  const int* rated_dst = (const int*)d_in[30];
  const int* uu_src = (const int*)d_in[31];
  const int* uu_dst = (const int*)d_in[32];

  // ---- workspace layout (~102 MB) ----
  ushort_t* ux = (ushort_t*)d_ws;                       // NU*128 bf16
  ushort_t* mx = ux + (size_t)NUSR * DH;                // NM*128
  ushort_t* agg = mx + (size_t)NMOV * DH;               // NU*128 (reused as pu; buckets alias here pre-lin)
  ushort_t* pm = agg + (size_t)NUSR * DH;               // NM*128
  ushort_t* Wt = pm + (size_t)NMOV * DH;                // 6 * 32768
  ushort_t* WtU = Wt + 6 * 32768;                       // 128*64
  ushort_t* WtM = WtU + 8192;                           // 128*128
  float* SEP = (float*)(WtM + 16384);                   // 128
  float* TEP = SEP + DH;                                // 128
  int* col_m = (int*)(TEP + DH);                        // NMOV*CAPM ints
  ushort_t* col_u = (ushort_t*)(col_m + (size_t)NMOV * CAPM);   // NUSR*CAPU ushorts
  int* col_uu = (int*)(col_u + (size_t)NUSR * CAPU);    // NUSR*CAPUU ints
  int* cntbuf = col_uu + (size_t)NUSR * CAPUU;          // NMOV+2*NUSR+NBT (16B-aligned)
  uchar_t* ux8 = (uchar_t*)(cntbuf + (NMOV + 2 * NUSR + NBT));  // NU*128 fp8
  uchar_t* mx8 = ux8 + (size_t)NUSR * DH;               // NM*128 fp8
  int* cnt_m = cntbuf;
  int* cnt_u = cntbuf + NMOV;
  int* cnt_uu = cntbuf + NMOV + NUSR;
  int* bcnt = cntbuf + NMOV + 2 * NUSR;                 // NBT bucket cursors

  // edge buckets alias agg (11 MB < 25.6 MB; agg first written by agg_mean4_k,
  // which launches after csr_k has drained the buckets)
  unsigned* bkt_d = (unsigned*)agg;
  unsigned* bkt_s = bkt_d + (size_t)NBD * BKD;
  unsigned* bkt_u = bkt_s + (size_t)NBS * BKS;

  ushort_t* Wt_u2m1 = Wt + 0 * 32768;
  ushort_t* Wt_m2u1 = Wt + 1 * 32768;
  ushort_t* Wt_u2m2 = Wt + 2 * 32768;
  ushort_t* Wt_m2u2 = Wt + 3 * 32768;
  ushort_t* Wt_u2u  = Wt + 4 * 32768;
  ushort_t* Wt_p1   = Wt + 5 * 32768;
  ushort_t* pu = agg;  // alias: agg dead after last sage layer

  // ---- fused weight prep + BN params + bcnt zero ----
  PrepArgs pa;
  pa.Wl[0] = u2m1_Wl; pa.Wr[0] = u2m1_Wr;
  pa.Wl[1] = m2u1_Wl; pa.Wr[1] = m2u1_Wr;
  pa.Wl[2] = u2m2_Wl; pa.Wr[2] = u2m2_Wr;
  pa.Wl[3] = m2u2_Wl; pa.Wr[3] = m2u2_Wr;
  pa.Wl[4] = u2u_Wl;  pa.Wr[4] = u2u_Wr;
  pa.Wl[5] = p1_W;    pa.Wr[5] = p1_W + DH * DH;
  prep_all_k<<<865, 256, 0, stream>>>(
      pa, Wt, W_user, W_movie, WtU, WtM,
      p1_b, bn_gamma, bn_beta, bn_mean, bn_var, SEP, TEP, bcnt);

  // ---- two-phase fill (fine bins -> LDS CSR assembly), then input linears ----
  bin_k<<<NBINB, 256, 0, stream>>>(
      rated_src, rated_dst, uu_src, uu_dst, bkt_d, bkt_s, bkt_u, bcnt);
  csr_k<<<NBT, 256, 0, stream>>>(
      bkt_d, bkt_s, bkt_u, bcnt, cnt_m, cnt_u, cnt_uu, col_m, col_u, col_uu);
  lin2_k<<<GLU + GLM, 256, 0, stream>>>(
      user_feat, WtU, b_user, ux, ux8, movie_feat, WtM, b_movie, mx, mx8);

  // ---- 5 SAGE layers (fp8 gather + bf16 MFMA) ----
  const int gaM = (NMOV + 15) / 16, gaU = (NUSR + 15) / 16;
  const int gmM = (NMOV + 127) / 128, gmU = (NUSR + 127) / 128;
  // u2m1: gather ux8 -> agg; update mx (+mx8, needed by m2u1 agg)
  agg_mean4_k<int, CAPM, 16><<<gaM, 256, 0, stream>>>(ux8, cnt_m, col_m, agg, NMOV);
  sage_mfma_k<<<gmM, 256, 0, stream>>>(agg, mx, Wt_u2m1, u2m1_bl, mx, mx8, NMOV);
  // m2u1: gather mx8 -> agg; update ux (+ux8, needed by u2m2 agg)
  agg_mean4_k<ushort_t, CAPU, 8><<<gaU, 256, 0, stream>>>(mx8, cnt_u, col_u, agg, NUSR);
  sage_mfma_k<<<gmU, 256, 0, stream>>>(agg, ux, Wt_m2u1, m2u1_bl, ux, ux8, NUSR);
  // u2m2
  agg_mean4_k<int, CAPM, 16><<<gaM, 256, 0, stream>>>(ux8, cnt_m, col_m, agg, NMOV);
  sage_mfma_k<<<gmM, 256, 0, stream>>>(agg, mx, Wt_u2m2, u2m2_bl, mx, mx8, NMOV);
  // m2u2
  agg_mean4_k<ushort_t, CAPU, 8><<<gaU, 256, 0, stream>>>(mx8, cnt_u, col_u, agg, NUSR);
  sage_mfma_k<<<gmU, 256, 0, stream>>>(agg, ux, Wt_m2u2, m2u2_bl, ux, ux8, NUSR);
  // u2u: final user layer; fp8 copy no longer needed afterwards
  agg_mean4_k<int, CAPUU, 8><<<gaU, 256, 0, stream>>>(ux8, cnt_uu, col_uu, agg, NUSR);
  sage_mfma_k<<<gmU, 256, 0, stream>>>(agg, ux, Wt_u2u, u2u_bl, ux, (uchar_t*)nullptr, NUSR);

  // ---- factored edge MLP (bf16 throughout) ----
  proj2_k<<<gmU + gmM, 256, 0, stream>>>(ux, mx, Wt_p1, pu, pm, gmU);
  ep_edge_k<<<(NEDG + 127) / 128, 256, 0, stream>>>(
      pu, pm, rated_src, rated_dst, SEP, TEP, p2_W, p2_b, (float*)d_out, NEDG);
}